// Round 12
// baseline (180.327 us; speedup 1.0000x reference)
//
#include <hip/hip_runtime.h>
#include <math.h>

#define N_NODES 50000
#define D 128       // d_in == d_hid
#define D_OUT 64

typedef short bf16x8 __attribute__((ext_vector_type(8)));   // 8 bf16 (4 VGPR) MFMA frag
typedef float f32x4  __attribute__((ext_vector_type(4)));   // MFMA accumulator
typedef unsigned short u16x8 __attribute__((ext_vector_type(8)));

__device__ __forceinline__ unsigned short f_to_bf16(float f) {
    unsigned int u = __float_as_uint(f);
    u = (u + 0x7fffu + ((u >> 16) & 1u)) >> 16;   // RNE
    return (unsigned short)u;
}
__device__ __forceinline__ float bf16lo(unsigned int v) { return __uint_as_float(v << 16); }
__device__ __forceinline__ float bf16hi(unsigned int v) { return __uint_as_float(v & 0xffff0000u); }
__device__ __forceinline__ float bf16f(unsigned short v) { return __uint_as_float((unsigned int)v << 16); }

__device__ __forceinline__ void conv8(const float* __restrict__ src, unsigned short* __restrict__ dst, int i)
{
    float4 v0 = *reinterpret_cast<const float4*>(src + i);
    float4 v1 = *reinterpret_cast<const float4*>(src + i + 4);
    u16x8 o;
    o[0] = f_to_bf16(v0.x); o[1] = f_to_bf16(v0.y);
    o[2] = f_to_bf16(v0.z); o[3] = f_to_bf16(v0.w);
    o[4] = f_to_bf16(v1.x); o[5] = f_to_bf16(v1.y);
    o[6] = f_to_bf16(v1.z); o[7] = f_to_bf16(v1.w);
    *reinterpret_cast<u16x8*>(dst + i) = o;
}

__device__ __forceinline__ void acc_add(float* acc, uint4 v)
{
    acc[0] += bf16lo(v.x); acc[1] += bf16hi(v.x);
    acc[2] += bf16lo(v.y); acc[3] += bf16hi(v.y);
    acc[4] += bf16lo(v.z); acc[5] += bf16hi(v.z);
    acc[6] += bf16lo(v.w); acc[7] += bf16hi(v.w);
}

// ---------------------------------------------------------------------------
// Zero deg|cursor
// ---------------------------------------------------------------------------
__global__ __launch_bounds__(256) void zero_kernel(int* __restrict__ p, int n4)
{
    int i = blockIdx.x * 256 + threadIdx.x;
    if (i < n4) *reinterpret_cast<int4*>(p + i * 4) = make_int4(0, 0, 0, 0);
}

// ---------------------------------------------------------------------------
// Fused prep: conv_x | conv_w | hist, dispatched by block range.
// ---------------------------------------------------------------------------
__global__ __launch_bounds__(256) void prep_kernel(
    const float* __restrict__ x, unsigned short* __restrict__ xb,
    const float* __restrict__ w1l, const float* __restrict__ w1r,
    const float* __restrict__ w2l, const float* __restrict__ w2r,
    unsigned short* __restrict__ Wb,
    const int* __restrict__ dst, int* __restrict__ deg,
    int XB, int E)
{
    const int bx = blockIdx.x;
    if (bx < XB) {
        int i = (bx * 256 + threadIdx.x) * 8;
        if (i < N_NODES * D) conv8(x, xb, i);
    } else if (bx < XB + 24) {
        int i = ((bx - XB) * 256 + threadIdx.x) * 8;   // 49152 elems
        const float* src; int off;
        if      (i < 16384) { src = w1l; off = 0; }
        else if (i < 32768) { src = w1r; off = 16384; }
        else if (i < 40960) { src = w2l; off = 32768; }
        else                { src = w2r; off = 40960; }
        conv8(src, Wb + off, i - off);
    } else {
        int e = (bx - XB - 24) * 256 + threadIdx.x;
        if (e < E) atomicAdd(&deg[dst[e]], 1);
    }
}

// ---------------------------------------------------------------------------
// Hierarchical exclusive scan (3 tiny dispatches — dispatch gap IS the barrier)
// ---------------------------------------------------------------------------
__global__ __launch_bounds__(256) void scan1_kernel(
    const int* __restrict__ deg, int* __restrict__ part,
    int* __restrict__ bsum, int n)
{
    const int t = threadIdx.x;
    const int base = blockIdx.x * 1024 + t * 4;

    int a0 = 0, a1 = 0, a2 = 0, a3 = 0;
    if (base + 3 < n) {
        int4 v = *reinterpret_cast<const int4*>(deg + base);
        a0 = v.x; a1 = v.y; a2 = v.z; a3 = v.w;
    } else if (base < n) {
        a0 = deg[base];
        if (base + 1 < n) a1 = deg[base + 1];
        if (base + 2 < n) a2 = deg[base + 2];
    }
    const int s0 = a0, s1 = s0 + a1, s2 = s1 + a2, s3 = s2 + a3;

    const int lane = t & 63;
    int incl = s3;
#pragma unroll
    for (int off = 1; off < 64; off <<= 1) {
        int up = __shfl_up(incl, off);
        if (lane >= off) incl += up;
    }

    __shared__ int wsum[4];
    const int wid = t >> 6;
    if (lane == 63) wsum[wid] = incl;
    __syncthreads();

    int woff = 0;
#pragma unroll
    for (int w = 0; w < 4; ++w) woff += (w < wid) ? wsum[w] : 0;

    const int ex = woff + incl - s3;
    if (base + 3 < n) {
        int4 o; o.x = ex; o.y = ex + s0; o.z = ex + s1; o.w = ex + s2;
        *reinterpret_cast<int4*>(part + base) = o;
    } else if (base < n) {
        part[base] = ex;
        if (base + 1 < n) part[base + 1] = ex + s0;
        if (base + 2 < n) part[base + 2] = ex + s1;
    }
    if (t == 255) bsum[blockIdx.x] = woff + incl;
}

__global__ __launch_bounds__(64) void scan2_kernel(
    int* __restrict__ bsum, int* __restrict__ row_ptr, int nb, int n)
{
    const int t = threadIdx.x;
    int v = (t < nb) ? bsum[t] : 0;
    int incl = v;
#pragma unroll
    for (int off = 1; off < 64; off <<= 1) {
        int up = __shfl_up(incl, off);
        if (t >= off) incl += up;
    }
    if (t < nb) bsum[t] = incl - v;
    if (t == 63) row_ptr[n] = incl;
}

__global__ __launch_bounds__(256) void scan3_kernel(
    const int* __restrict__ part, const int* __restrict__ bsum,
    int* __restrict__ row_ptr, int n)
{
    const int base = blockIdx.x * 1024 + threadIdx.x * 4;
    const int add = bsum[blockIdx.x];
    if (base + 3 < n) {
        int4 v = *reinterpret_cast<const int4*>(part + base);
        v.x += add; v.y += add; v.z += add; v.w += add;
        *reinterpret_cast<int4*>(row_ptr + base) = v;
    } else if (base < n) {
        row_ptr[base] = part[base] + add;
        if (base + 1 < n) row_ptr[base + 1] = part[base + 1] + add;
        if (base + 2 < n) row_ptr[base + 2] = part[base + 2] + add;
    }
}

// ---------------------------------------------------------------------------
// CSR bucket-fill
// ---------------------------------------------------------------------------
__global__ __launch_bounds__(256) void fill_kernel(
    const int* __restrict__ src, const int* __restrict__ dst,
    const int* __restrict__ row_ptr, int* __restrict__ cursor,
    int* __restrict__ esrc, int E)
{
    int e = blockIdx.x * blockDim.x + threadIdx.x;
    if (e >= E) return;
    int d = dst[e];
    int pos = atomicAdd(&cursor[d], 1);
    esrc[row_ptr[d] + pos] = src[e];
}

// ---------------------------------------------------------------------------
// Fused gather(x) + layer1 + t2, 1024 threads = 16 waves = 16 nodes:
// gather phase = 1 node PER WAVE (restores round-9 gather TLP: 50k waves),
// then waves 0-7 compute jt slices 0-7, then waves 0-3 compute t2 jt 0-3.
// D-layout: col = lane&15, row = (lane>>4)*4 + reg   [m89 verified]
// ---------------------------------------------------------------------------
__global__ __launch_bounds__(1024) void gather_layer1_kernel(
    const unsigned short* __restrict__ xb,
    const int* __restrict__ row_ptr, const int* __restrict__ esrc,
    const unsigned short* __restrict__ Wb,   // W1l@0, W1r@16384, W2l@32768
    const float* __restrict__ b1,
    unsigned short* __restrict__ h1b, unsigned short* __restrict__ t2b)
{
    __shared__ unsigned short aggs[16][136];   // 272B rows: 16B-aligned, 2-way alias
    __shared__ unsigned short h1s[16][136];

    const int t = threadIdx.x;
    const int wv = t >> 6, lane = t & 63;
    const int node0 = blockIdx.x * 16;

    {   // ---- gather: wave wv owns node node0+wv ----
        const int node = node0 + wv;
        const int beg = row_ptr[node], end = row_ptr[node + 1];
        const int g = lane >> 4, c = lane & 15;   // 4 row slots x 16 chunks
        const uint4* x4 = reinterpret_cast<const uint4*>(xb);

        float acc[8];
#pragma unroll
        for (int k = 0; k < 8; ++k) acc[k] = 0.f;

        for (int base = beg; base < end; base += 64) {
            const int cnt = min(end - base, 64);
            int s = (base + lane < end) ? esrc[base + lane] : 0;
            for (int i = 0; i < cnt; i += 16) {
                int pp[4]; uint4 vv[4];
#pragma unroll
                for (int j = 0; j < 4; ++j) {
                    pp[j] = i + j * 4 + g;
                    int sj = __shfl(s, pp[j] & 63);
                    vv[j] = x4[(size_t)sj * 16 + c];
                }
#pragma unroll
                for (int j = 0; j < 4; ++j)
                    if (pp[j] < cnt) acc_add(acc, vv[j]);
            }
        }
#pragma unroll
        for (int k = 0; k < 8; ++k) {
            acc[k] += __shfl_xor(acc[k], 16);
            acc[k] += __shfl_xor(acc[k], 32);
        }
        if (g == 0) {
            const float inv = (end > beg) ? 1.0f / (float)(end - beg) : 0.0f;
            uint4 o;
            o.x = (unsigned int)f_to_bf16(acc[0] * inv) | ((unsigned int)f_to_bf16(acc[1] * inv) << 16);
            o.y = (unsigned int)f_to_bf16(acc[2] * inv) | ((unsigned int)f_to_bf16(acc[3] * inv) << 16);
            o.z = (unsigned int)f_to_bf16(acc[4] * inv) | ((unsigned int)f_to_bf16(acc[5] * inv) << 16);
            o.w = (unsigned int)f_to_bf16(acc[6] * inv) | ((unsigned int)f_to_bf16(acc[7] * inv) << 16);
            *reinterpret_cast<uint4*>(&aggs[wv][c * 8]) = o;
        }
    }
    __syncthreads();

    const int c16 = lane & 15, kg = lane >> 4;

    if (wv < 8) {   // ---- layer1: wave wv computes jt = wv ----
        const int jt = wv;
        bf16x8 aL[4], aR[4];
#pragma unroll
        for (int kf = 0; kf < 4; ++kf) {
            aL[kf] = *reinterpret_cast<const bf16x8*>(&aggs[c16][kg * 8 + kf * 32]);
            aR[kf] = *reinterpret_cast<const bf16x8*>(xb + (size_t)(node0 + c16) * D + kg * 8 + kf * 32);
        }
        f32x4 acc = {0.f, 0.f, 0.f, 0.f};
        const unsigned short* wl = Wb +         (size_t)(jt * 16 + c16) * D + kg * 8;
        const unsigned short* wr = Wb + 16384 + (size_t)(jt * 16 + c16) * D + kg * 8;
#pragma unroll
        for (int kf = 0; kf < 4; ++kf) {
            bf16x8 b = *reinterpret_cast<const bf16x8*>(wl + kf * 32);
            acc = __builtin_amdgcn_mfma_f32_16x16x32_bf16(aL[kf], b, acc, 0, 0, 0);
        }
#pragma unroll
        for (int kf = 0; kf < 4; ++kf) {
            bf16x8 b = *reinterpret_cast<const bf16x8*>(wr + kf * 32);
            acc = __builtin_amdgcn_mfma_f32_16x16x32_bf16(aR[kf], b, acc, 0, 0, 0);
        }
        const float bias = b1[jt * 16 + c16];
#pragma unroll
        for (int i = 0; i < 4; ++i) {
            float v = fmaxf(acc[i] + bias, 0.0f);
            unsigned short us = f_to_bf16(v);
            h1b[(size_t)(node0 + kg * 4 + i) * D + jt * 16 + c16] = us;
            h1s[kg * 4 + i][jt * 16 + c16] = us;
        }
    }
    __syncthreads();

    if (wv < 4) {   // ---- t2: wave wv computes jt = wv ----
        const int jt = wv;
        bf16x8 a2[4];
#pragma unroll
        for (int kf = 0; kf < 4; ++kf)
            a2[kf] = *reinterpret_cast<const bf16x8*>(&h1s[c16][kg * 8 + kf * 32]);
        f32x4 acc = {0.f, 0.f, 0.f, 0.f};
        const unsigned short* wl = Wb + 32768 + (size_t)(jt * 16 + c16) * D + kg * 8;
#pragma unroll
        for (int kf = 0; kf < 4; ++kf) {
            bf16x8 b = *reinterpret_cast<const bf16x8*>(wl + kf * 32);
            acc = __builtin_amdgcn_mfma_f32_16x16x32_bf16(a2[kf], b, acc, 0, 0, 0);
        }
#pragma unroll
        for (int i = 0; i < 4; ++i)
            t2b[(size_t)(node0 + kg * 4 + i) * D_OUT + jt * 16 + c16] = f_to_bf16(acc[i]);
    }
}

// ---------------------------------------------------------------------------
// Fused gather(t2, 128B rows) + layer2 right GEMM + log_softmax.
// 1024 threads = 16 waves = 16 nodes; 1 node per wave in the gather.
// ---------------------------------------------------------------------------
__global__ __launch_bounds__(1024) void gather_layer2_kernel(
    const unsigned short* __restrict__ t2b,
    const unsigned short* __restrict__ h1b,
    const int* __restrict__ row_ptr, const int* __restrict__ esrc,
    const unsigned short* __restrict__ Wb,   // W2r@40960
    const float* __restrict__ b2, float* __restrict__ out)
{
    __shared__ unsigned short agg2s[16][72];   // 144B rows
    __shared__ float zs[16][68];               // 272B rows

    const int t = threadIdx.x;
    const int wv = t >> 6, lane = t & 63;
    const int node0 = blockIdx.x * 16;

    {   // ---- gather: wave wv owns node node0+wv (128B rows) ----
        const int node = node0 + wv;
        const int beg = row_ptr[node], end = row_ptr[node + 1];
        const int g = lane >> 3, c = lane & 7;     // 8 row slots x 8 chunks
        const uint4* t4 = reinterpret_cast<const uint4*>(t2b);

        float acc[8];
#pragma unroll
        for (int k = 0; k < 8; ++k) acc[k] = 0.f;

        for (int base = beg; base < end; base += 64) {
            const int cnt = min(end - base, 64);
            int s = (base + lane < end) ? esrc[base + lane] : 0;
            for (int i = 0; i < cnt; i += 16) {
                int pp[2]; uint4 vv[2];
#pragma unroll
                for (int j = 0; j < 2; ++j) {
                    pp[j] = i + j * 8 + g;
                    int sj = __shfl(s, pp[j] & 63);
                    vv[j] = t4[(size_t)sj * 8 + c];
                }
#pragma unroll
                for (int j = 0; j < 2; ++j)
                    if (pp[j] < cnt) acc_add(acc, vv[j]);
            }
        }
#pragma unroll
        for (int k = 0; k < 8; ++k) {
            acc[k] += __shfl_xor(acc[k], 8);
            acc[k] += __shfl_xor(acc[k], 16);
            acc[k] += __shfl_xor(acc[k], 32);
        }
        if (g == 0) {
            const float inv = (end > beg) ? 1.0f / (float)(end - beg) : 0.0f;
            uint4 o;
            o.x = (unsigned int)f_to_bf16(acc[0] * inv) | ((unsigned int)f_to_bf16(acc[1] * inv) << 16);
            o.y = (unsigned int)f_to_bf16(acc[2] * inv) | ((unsigned int)f_to_bf16(acc[3] * inv) << 16);
            o.z = (unsigned int)f_to_bf16(acc[4] * inv) | ((unsigned int)f_to_bf16(acc[5] * inv) << 16);
            o.w = (unsigned int)f_to_bf16(acc[6] * inv) | ((unsigned int)f_to_bf16(acc[7] * inv) << 16);
            *reinterpret_cast<uint4*>(&agg2s[wv][c * 8]) = o;
        }
    }
    __syncthreads();

    if (wv < 4) {   // ---- right GEMM slice jt = wv; z staged to LDS ----
        const int c16 = lane & 15, kg = lane >> 4;
        const int jt = wv;
        bf16x8 a[4];
#pragma unroll
        for (int kf = 0; kf < 4; ++kf)
            a[kf] = *reinterpret_cast<const bf16x8*>(h1b + (size_t)(node0 + c16) * D + kg * 8 + kf * 32);
        f32x4 acc = {0.f, 0.f, 0.f, 0.f};
        const unsigned short* wr = Wb + 40960 + (size_t)(jt * 16 + c16) * D + kg * 8;
#pragma unroll
        for (int kf = 0; kf < 4; ++kf) {
            bf16x8 b = *reinterpret_cast<const bf16x8*>(wr + kf * 32);
            acc = __builtin_amdgcn_mfma_f32_16x16x32_bf16(a[kf], b, acc, 0, 0, 0);
        }
        const float bias = b2[jt * 16 + c16];
#pragma unroll
        for (int i = 0; i < 4; ++i) {
            const int row = kg * 4 + i;
            float left = bf16f(agg2s[row][jt * 16 + c16]);
            zs[row][jt * 16 + c16] = left + acc[i] + bias;
        }
    }
    __syncthreads();

    {   // ---- softmax: wave wv handles row wv (64-lane reduce) ----
        float z = zs[wv][lane];
        float m = z;
#pragma unroll
        for (int off = 1; off < 64; off <<= 1)
            m = fmaxf(m, __shfl_xor(m, off));
        float e = expf(z - m);
        float s = e;
#pragma unroll
        for (int off = 1; off < 64; off <<= 1)
            s += __shfl_xor(s, off);
        out[(size_t)(node0 + wv) * D_OUT + lane] = z - m - logf(s);
    }
}

// ---------------------------------------------------------------------------
extern "C" void kernel_launch(void* const* d_in, const int* in_sizes, int n_in,
                              void* d_out, int out_size, void* d_ws, size_t ws_size,
                              hipStream_t stream)
{
    const float* x   = (const float*)d_in[0];
    const int*   ei  = (const int*)d_in[1];
    const float* W1l = (const float*)d_in[2];
    const float* b1  = (const float*)d_in[3];
    const float* W1r = (const float*)d_in[4];
    const float* W2l = (const float*)d_in[5];
    const float* b2  = (const float*)d_in[6];
    const float* W2r = (const float*)d_in[7];
    float* out = (float*)d_out;

    const int E = in_sizes[1] / 2;
    const int* src = ei;
    const int* dst = ei + E;

    // ---- workspace layout (256B-aligned chunks) ----
    char* base = (char*)d_ws;
    size_t off = 0;
    auto take = [&](size_t bytes) { char* p = base + off; off += (bytes + 255) & ~(size_t)255; return p; };

    unsigned short* xb  = (unsigned short*)take((size_t)N_NODES * D * 2);
    unsigned short* h1b = (unsigned short*)take((size_t)N_NODES * D * 2);
    unsigned short* t2b = (unsigned short*)take((size_t)N_NODES * D_OUT * 2);
    unsigned short* Wb  = (unsigned short*)take((size_t)49152 * 2);
    int* degcur  = (int*)take((size_t)2 * N_NODES * 4);   // deg | cursor
    int* deg     = degcur;
    int* cursor  = degcur + N_NODES;
    int* row_ptr = (int*)take(((size_t)N_NODES + 1) * 4);
    int* part    = (int*)take((size_t)N_NODES * 4);
    int* bsum    = (int*)take((size_t)64 * 4);
    int* esrc    = (int*)take((size_t)E * 4);

    const int EB = (E + 255) / 256;
    const int SB = (N_NODES + 1023) / 1024;       // 49 scan blocks
    const int XB = (N_NODES * D / 8 + 255) / 256; // 3125 conv_x blocks
    const int MB = N_NODES / 16;                  // 3125 tile blocks, exact

    zero_kernel<<<(2 * N_NODES / 4 + 255) / 256, 256, 0, stream>>>(degcur, 2 * N_NODES / 4);
    prep_kernel<<<XB + 24 + EB, 256, 0, stream>>>(x, xb, W1l, W1r, W2l, W2r, Wb, dst, deg, XB, E);
    scan1_kernel<<<SB, 256, 0, stream>>>(deg, part, bsum, N_NODES);
    scan2_kernel<<<1, 64, 0, stream>>>(bsum, row_ptr, SB, N_NODES);
    scan3_kernel<<<SB, 256, 0, stream>>>(part, bsum, row_ptr, N_NODES);
    fill_kernel<<<EB, 256, 0, stream>>>(src, dst, row_ptr, cursor, esrc, E);

    // fused gather + layer kernels: 16 waves/block, 1 node per wave
    gather_layer1_kernel<<<MB, 1024, 0, stream>>>(xb, row_ptr, esrc, Wb, b1, h1b, t2b);
    gather_layer2_kernel<<<MB, 1024, 0, stream>>>(t2b, h1b, row_ptr, esrc, Wb, b2, out);
}

// Round 13
// 166.492 us; speedup vs baseline: 1.0831x; 1.0831x over previous
//
#include <hip/hip_runtime.h>
#include <math.h>

#define N_NODES 50000
#define D 128       // d_in == d_hid
#define D_OUT 64

typedef short bf16x8 __attribute__((ext_vector_type(8)));   // 8 bf16 (4 VGPR) MFMA frag
typedef float f32x4  __attribute__((ext_vector_type(4)));   // MFMA accumulator
typedef unsigned short u16x8 __attribute__((ext_vector_type(8)));

__device__ __forceinline__ unsigned short f_to_bf16(float f) {
    unsigned int u = __float_as_uint(f);
    u = (u + 0x7fffu + ((u >> 16) & 1u)) >> 16;   // RNE
    return (unsigned short)u;
}
__device__ __forceinline__ float bf16lo(unsigned int v) { return __uint_as_float(v << 16); }
__device__ __forceinline__ float bf16hi(unsigned int v) { return __uint_as_float(v & 0xffff0000u); }
__device__ __forceinline__ float bf16f(unsigned short v) { return __uint_as_float((unsigned int)v << 16); }

__device__ __forceinline__ void conv8(const float* __restrict__ src, unsigned short* __restrict__ dst, int i)
{
    float4 v0 = *reinterpret_cast<const float4*>(src + i);
    float4 v1 = *reinterpret_cast<const float4*>(src + i + 4);
    u16x8 o;
    o[0] = f_to_bf16(v0.x); o[1] = f_to_bf16(v0.y);
    o[2] = f_to_bf16(v0.z); o[3] = f_to_bf16(v0.w);
    o[4] = f_to_bf16(v1.x); o[5] = f_to_bf16(v1.y);
    o[6] = f_to_bf16(v1.z); o[7] = f_to_bf16(v1.w);
    *reinterpret_cast<u16x8*>(dst + i) = o;
}

__device__ __forceinline__ void acc_add(float* acc, uint4 v)
{
    acc[0] += bf16lo(v.x); acc[1] += bf16hi(v.x);
    acc[2] += bf16lo(v.y); acc[3] += bf16hi(v.y);
    acc[4] += bf16lo(v.z); acc[5] += bf16hi(v.z);
    acc[6] += bf16lo(v.w); acc[7] += bf16hi(v.w);
}

// ---------------------------------------------------------------------------
// Zero deg|cursor
// ---------------------------------------------------------------------------
__global__ __launch_bounds__(256) void zero_kernel(int* __restrict__ p, int n4)
{
    int i = blockIdx.x * 256 + threadIdx.x;
    if (i < n4) *reinterpret_cast<int4*>(p + i * 4) = make_int4(0, 0, 0, 0);
}

// ---------------------------------------------------------------------------
// Fused prep: conv_x | conv_w | hist, dispatched by block range.
// ---------------------------------------------------------------------------
__global__ __launch_bounds__(256) void prep_kernel(
    const float* __restrict__ x, unsigned short* __restrict__ xb,
    const float* __restrict__ w1l, const float* __restrict__ w1r,
    const float* __restrict__ w2l, const float* __restrict__ w2r,
    unsigned short* __restrict__ Wb,
    const int* __restrict__ dst, int* __restrict__ deg,
    int XB, int E)
{
    const int bx = blockIdx.x;
    if (bx < XB) {
        int i = (bx * 256 + threadIdx.x) * 8;
        if (i < N_NODES * D) conv8(x, xb, i);
    } else if (bx < XB + 24) {
        int i = ((bx - XB) * 256 + threadIdx.x) * 8;   // 49152 elems
        const float* src; int off;
        if      (i < 16384) { src = w1l; off = 0; }
        else if (i < 32768) { src = w1r; off = 16384; }
        else if (i < 40960) { src = w2l; off = 32768; }
        else                { src = w2r; off = 40960; }
        conv8(src, Wb + off, i - off);
    } else {
        int e = (bx - XB - 24) * 256 + threadIdx.x;
        if (e < E) atomicAdd(&deg[dst[e]], 1);
    }
}

// ---------------------------------------------------------------------------
// Scan step 1: per-block (1024 elems) local exclusive scan + block sums
// ---------------------------------------------------------------------------
__global__ __launch_bounds__(256) void scan1_kernel(
    const int* __restrict__ deg, int* __restrict__ part,
    int* __restrict__ bsum, int n)
{
    const int t = threadIdx.x;
    const int base = blockIdx.x * 1024 + t * 4;

    int a0 = 0, a1 = 0, a2 = 0, a3 = 0;
    if (base + 3 < n) {
        int4 v = *reinterpret_cast<const int4*>(deg + base);
        a0 = v.x; a1 = v.y; a2 = v.z; a3 = v.w;
    } else if (base < n) {
        a0 = deg[base];
        if (base + 1 < n) a1 = deg[base + 1];
        if (base + 2 < n) a2 = deg[base + 2];
    }
    const int s0 = a0, s1 = s0 + a1, s2 = s1 + a2, s3 = s2 + a3;

    const int lane = t & 63;
    int incl = s3;
#pragma unroll
    for (int off = 1; off < 64; off <<= 1) {
        int up = __shfl_up(incl, off);
        if (lane >= off) incl += up;
    }

    __shared__ int wsum[4];
    const int wid = t >> 6;
    if (lane == 63) wsum[wid] = incl;
    __syncthreads();

    int woff = 0;
#pragma unroll
    for (int w = 0; w < 4; ++w) woff += (w < wid) ? wsum[w] : 0;

    const int ex = woff + incl - s3;
    if (base + 3 < n) {
        int4 o; o.x = ex; o.y = ex + s0; o.z = ex + s1; o.w = ex + s2;
        *reinterpret_cast<int4*>(part + base) = o;
    } else if (base < n) {
        part[base] = ex;
        if (base + 1 < n) part[base + 1] = ex + s0;
        if (base + 2 < n) part[base + 2] = ex + s1;
    }
    if (t == 255) bsum[blockIdx.x] = woff + incl;
}

// ---------------------------------------------------------------------------
// Scan step 2 (absorbs old scan2): each block redundantly computes its offset
// from the 49 block sums (64-lane masked reduce — validated in round 10 ph3),
// then adds it to part -> row_ptr. Last block writes row_ptr[n] = total.
// ---------------------------------------------------------------------------
__global__ __launch_bounds__(256) void scan3_kernel(
    const int* __restrict__ part, const int* __restrict__ bsum,
    int* __restrict__ row_ptr, int nb, int n)
{
    __shared__ int sAdd, sTot;
    const int t = threadIdx.x;
    const int bid = blockIdx.x;

    if (t < 64) {
        int v   = (t < nb) ? bsum[t] : 0;
        int add = (t < bid) ? v : 0;
        int tot = v;
#pragma unroll
        for (int off = 1; off < 64; off <<= 1) {
            add += __shfl_xor(add, off);
            tot += __shfl_xor(tot, off);
        }
        if (t == 0) { sAdd = add; sTot = tot; }
    }
    __syncthreads();

    const int add = sAdd;
    const int base = bid * 1024 + t * 4;
    if (base + 3 < n) {
        int4 v = *reinterpret_cast<const int4*>(part + base);
        v.x += add; v.y += add; v.z += add; v.w += add;
        *reinterpret_cast<int4*>(row_ptr + base) = v;
    } else if (base < n) {
        row_ptr[base] = part[base] + add;
        if (base + 1 < n) row_ptr[base + 1] = part[base + 1] + add;
        if (base + 2 < n) row_ptr[base + 2] = part[base + 2] + add;
    }
    if (bid == nb - 1 && t == 0) row_ptr[n] = sTot;
}

// ---------------------------------------------------------------------------
// CSR bucket-fill
// ---------------------------------------------------------------------------
__global__ __launch_bounds__(256) void fill_kernel(
    const int* __restrict__ src, const int* __restrict__ dst,
    const int* __restrict__ row_ptr, int* __restrict__ cursor,
    int* __restrict__ esrc, int E)
{
    int e = blockIdx.x * blockDim.x + threadIdx.x;
    if (e >= E) return;
    int d = dst[e];
    int pos = atomicAdd(&cursor[d], 1);
    esrc[row_ptr[d] + pos] = src[e];
}

// ---------------------------------------------------------------------------
// Gather-aggregate, 1 wave/node (4 waves/block), templated on CHUNKS
// (uint4 chunks per row). PREDICATED loads: zero wasted L3 reads, and a
// deg-d node still gets ceil(d/RPL) independent loads in flight at once.
//   CHUNKS=16 (256B rows): RPL=4,  NLOADS=8 -> 32 rows/iter
//   CHUNKS=8  (128B rows): RPL=8,  NLOADS=8 -> 64 rows/iter
// ---------------------------------------------------------------------------
template<int CHUNKS>
__global__ __launch_bounds__(256) void gather_bf16_kernel(
    const unsigned short* __restrict__ xb,
    const int* __restrict__ row_ptr,
    const int* __restrict__ esrc,
    unsigned short* __restrict__ aggb,
    int n_nodes)
{
    constexpr int RPL = 64 / CHUNKS;        // rows per load instr
    constexpr int NLOADS = 8;               // predicated loads per iter
    constexpr int ITER = RPL * NLOADS;      // rows per iteration
    const int wv   = threadIdx.x >> 6;
    const int lane = threadIdx.x & 63;
    const int node = blockIdx.x * 4 + wv;
    if (node >= n_nodes) return;

    const int beg = row_ptr[node];
    const int end = row_ptr[node + 1];
    const int g = lane / CHUNKS;            // row slot within load
    const int c = lane % CHUNKS;            // 16B column chunk

    const uint4* x4 = reinterpret_cast<const uint4*>(xb);

    float acc[8];
#pragma unroll
    for (int k = 0; k < 8; ++k) acc[k] = 0.f;

    for (int base = beg; base < end; base += 64) {
        const int cnt = min(end - base, 64);
        int s = (base + lane < end) ? esrc[base + lane] : 0;
        for (int i = 0; i < cnt; i += ITER) {
            int pp[NLOADS]; uint4 vv[NLOADS]; bool ok[NLOADS];
#pragma unroll
            for (int j = 0; j < NLOADS; ++j) {
                pp[j] = i + j * RPL + g;
                int sj = __shfl(s, pp[j] & 63);
                ok[j] = pp[j] < cnt;
                if (ok[j]) vv[j] = x4[(size_t)sj * CHUNKS + c];
            }
#pragma unroll
            for (int j = 0; j < NLOADS; ++j)
                if (ok[j]) acc_add(acc, vv[j]);
        }
    }

    // combine row-slot groups (lanes sharing chunk c)
#pragma unroll
    for (int k = 0; k < 8; ++k) {
#pragma unroll
        for (int off = CHUNKS; off < 64; off <<= 1)
            acc[k] += __shfl_xor(acc[k], off);
    }

    if (g == 0) {
        const float inv = (end > beg) ? 1.0f / (float)(end - beg) : 0.0f;
        uint4 o;
        o.x = (unsigned int)f_to_bf16(acc[0] * inv) | ((unsigned int)f_to_bf16(acc[1] * inv) << 16);
        o.y = (unsigned int)f_to_bf16(acc[2] * inv) | ((unsigned int)f_to_bf16(acc[3] * inv) << 16);
        o.z = (unsigned int)f_to_bf16(acc[4] * inv) | ((unsigned int)f_to_bf16(acc[5] * inv) << 16);
        o.w = (unsigned int)f_to_bf16(acc[6] * inv) | ((unsigned int)f_to_bf16(acc[7] * inv) << 16);
        reinterpret_cast<uint4*>(aggb)[(size_t)node * CHUNKS + c] = o;
    }
}

// ---------------------------------------------------------------------------
// Layer 1 via MFMA 16x16x32 bf16, one wave per 16-node tile.
// Also emits t2 = h1 · W2l^T ([N,64] bf16) so layer-2 gathers 128B rows
// (linearity: mean(h1)·Wl = mean(h1·Wl)).
// D-layout: col = lane&15, row = (lane>>4)*4 + reg   [m89 verified]
// ---------------------------------------------------------------------------
__global__ __launch_bounds__(64) void layer1_mfma_kernel(
    const unsigned short* __restrict__ aggb,
    const unsigned short* __restrict__ xb,
    const unsigned short* __restrict__ Wb,   // W1l@0, W1r@16384, W2l@32768
    const float* __restrict__ b1,
    unsigned short* __restrict__ h1b,
    unsigned short* __restrict__ t2b)        // [N,64]
{
    __shared__ unsigned short h1s[16][144];  // padded: 288B rows, 16B-aligned

    const int lane  = threadIdx.x;
    const int node0 = blockIdx.x * 16;
    const int c16   = lane & 15;
    const int kg    = lane >> 4;

    bf16x8 a[2][4];
    {
        const unsigned short* A0 = aggb + (size_t)(node0 + c16) * D + kg * 8;
        const unsigned short* A1 = xb   + (size_t)(node0 + c16) * D + kg * 8;
#pragma unroll
        for (int kf = 0; kf < 4; ++kf) {
            a[0][kf] = *reinterpret_cast<const bf16x8*>(A0 + kf * 32);
            a[1][kf] = *reinterpret_cast<const bf16x8*>(A1 + kf * 32);
        }
    }
    const unsigned short* WL = Wb;
    const unsigned short* WR = Wb + 16384;

#pragma unroll 2
    for (int jt = 0; jt < 8; ++jt) {
        f32x4 acc = {0.f, 0.f, 0.f, 0.f};
        const unsigned short* wl = WL + (size_t)(jt * 16 + c16) * D + kg * 8;
        const unsigned short* wr = WR + (size_t)(jt * 16 + c16) * D + kg * 8;
#pragma unroll
        for (int kf = 0; kf < 4; ++kf) {
            bf16x8 b = *reinterpret_cast<const bf16x8*>(wl + kf * 32);
            acc = __builtin_amdgcn_mfma_f32_16x16x32_bf16(a[0][kf], b, acc, 0, 0, 0);
        }
#pragma unroll
        for (int kf = 0; kf < 4; ++kf) {
            bf16x8 b = *reinterpret_cast<const bf16x8*>(wr + kf * 32);
            acc = __builtin_amdgcn_mfma_f32_16x16x32_bf16(a[1][kf], b, acc, 0, 0, 0);
        }
        const float bias = b1[jt * 16 + c16];
#pragma unroll
        for (int i = 0; i < 4; ++i) {
            float v = fmaxf(acc[i] + bias, 0.0f);
            unsigned short us = f_to_bf16(v);
            h1b[(size_t)(node0 + kg * 4 + i) * D + jt * 16 + c16] = us;
            h1s[kg * 4 + i][jt * 16 + c16] = us;
        }
    }

    __syncthreads();

    // t2 = h1_tile (16x128) · W2l^T -> 16x64
    bf16x8 a2[4];
#pragma unroll
    for (int kf = 0; kf < 4; ++kf)
        a2[kf] = *reinterpret_cast<const bf16x8*>(&h1s[c16][kg * 8 + kf * 32]);

    const unsigned short* W2L = Wb + 32768;
#pragma unroll
    for (int jt = 0; jt < 4; ++jt) {
        f32x4 acc = {0.f, 0.f, 0.f, 0.f};
        const unsigned short* wl = W2L + (size_t)(jt * 16 + c16) * D + kg * 8;
#pragma unroll
        for (int kf = 0; kf < 4; ++kf) {
            bf16x8 b = *reinterpret_cast<const bf16x8*>(wl + kf * 32);
            acc = __builtin_amdgcn_mfma_f32_16x16x32_bf16(a2[kf], b, acc, 0, 0, 0);
        }
#pragma unroll
        for (int i = 0; i < 4; ++i)
            t2b[(size_t)(node0 + kg * 4 + i) * D_OUT + jt * 16 + c16] = f_to_bf16(acc[i]);
    }
}

// ---------------------------------------------------------------------------
// Layer 2: out = log_softmax( agg(t2) + b2 + h1·W2r^T ).
// Left term arrives premeaned in agg2b [N,64]; only the right GEMM remains.
// ---------------------------------------------------------------------------
__global__ __launch_bounds__(64) void layer2_mfma_kernel(
    const unsigned short* __restrict__ agg2b,   // [N,64] premeaned t2
    const unsigned short* __restrict__ h1b,
    const unsigned short* __restrict__ Wb,      // W2r@40960
    const float* __restrict__ b2,
    float* __restrict__ out)
{
    const int lane  = threadIdx.x;
    const int node0 = blockIdx.x * 16;
    const int c16   = lane & 15;
    const int kg    = lane >> 4;

    bf16x8 a[4];
    {
        const unsigned short* A1 = h1b + (size_t)(node0 + c16) * D + kg * 8;
#pragma unroll
        for (int kf = 0; kf < 4; ++kf)
            a[kf] = *reinterpret_cast<const bf16x8*>(A1 + kf * 32);
    }
    const unsigned short* WR = Wb + 40960;

    f32x4 accs[4];
#pragma unroll
    for (int jt = 0; jt < 4; ++jt) {
        f32x4 acc = {0.f, 0.f, 0.f, 0.f};
        const unsigned short* wr = WR + (size_t)(jt * 16 + c16) * D + kg * 8;
#pragma unroll
        for (int kf = 0; kf < 4; ++kf) {
            bf16x8 b = *reinterpret_cast<const bf16x8*>(wr + kf * 32);
            acc = __builtin_amdgcn_mfma_f32_16x16x32_bf16(a[kf], b, acc, 0, 0, 0);
        }
        accs[jt] = acc;
    }

    float bias[4];
#pragma unroll
    for (int jt = 0; jt < 4; ++jt) bias[jt] = b2[jt * 16 + c16];

#pragma unroll
    for (int i = 0; i < 4; ++i) {
        const int node = node0 + kg * 4 + i;
        float z[4];
        float m = -1e30f;
#pragma unroll
        for (int jt = 0; jt < 4; ++jt) {
            float lft = bf16f(agg2b[(size_t)node * D_OUT + jt * 16 + c16]);
            z[jt] = lft + accs[jt][i] + bias[jt];
            m = fmaxf(m, z[jt]);
        }
#pragma unroll
        for (int off = 1; off < 16; off <<= 1)
            m = fmaxf(m, __shfl_xor(m, off));
        float s = 0.f;
#pragma unroll
        for (int jt = 0; jt < 4; ++jt) s += expf(z[jt] - m);
#pragma unroll
        for (int off = 1; off < 16; off <<= 1)
            s += __shfl_xor(s, off);
        float lse = m + logf(s);
#pragma unroll
        for (int jt = 0; jt < 4; ++jt)
            out[(size_t)node * D_OUT + jt * 16 + c16] = z[jt] - lse;
    }
}

// ---------------------------------------------------------------------------
extern "C" void kernel_launch(void* const* d_in, const int* in_sizes, int n_in,
                              void* d_out, int out_size, void* d_ws, size_t ws_size,
                              hipStream_t stream)
{
    const float* x   = (const float*)d_in[0];
    const int*   ei  = (const int*)d_in[1];
    const float* W1l = (const float*)d_in[2];
    const float* b1  = (const float*)d_in[3];
    const float* W1r = (const float*)d_in[4];
    const float* W2l = (const float*)d_in[5];
    const float* b2  = (const float*)d_in[6];
    const float* W2r = (const float*)d_in[7];
    float* out = (float*)d_out;

    const int E = in_sizes[1] / 2;
    const int* src = ei;
    const int* dst = ei + E;

    // ---- workspace layout (256B-aligned chunks) ----
    char* base = (char*)d_ws;
    size_t off = 0;
    auto take = [&](size_t bytes) { char* p = base + off; off += (bytes + 255) & ~(size_t)255; return p; };

    unsigned short* xb    = (unsigned short*)take((size_t)N_NODES * D * 2);
    unsigned short* aggb  = (unsigned short*)take((size_t)N_NODES * D * 2);
    unsigned short* h1b   = (unsigned short*)take((size_t)N_NODES * D * 2);
    unsigned short* t2b   = (unsigned short*)take((size_t)N_NODES * D_OUT * 2);
    unsigned short* agg2b = (unsigned short*)take((size_t)N_NODES * D_OUT * 2);
    unsigned short* Wb    = (unsigned short*)take((size_t)49152 * 2);
    int* degcur  = (int*)take((size_t)2 * N_NODES * 4);   // deg | cursor
    int* deg     = degcur;
    int* cursor  = degcur + N_NODES;
    int* row_ptr = (int*)take(((size_t)N_NODES + 1) * 4);
    int* part    = (int*)take((size_t)N_NODES * 4);
    int* bsum    = (int*)take((size_t)64 * 4);
    int* esrc    = (int*)take((size_t)E * 4);

    const int EB = (E + 255) / 256;
    const int SB = (N_NODES + 1023) / 1024;       // 49 scan blocks
    const int XB = (N_NODES * D / 8 + 255) / 256; // 3125 conv_x blocks
    const int GB = (N_NODES + 3) / 4;             // gather: 4 nodes per block
    const int MB = N_NODES / 16;                  // 3125 tile blocks, exact

    zero_kernel<<<(2 * N_NODES / 4 + 255) / 256, 256, 0, stream>>>(degcur, 2 * N_NODES / 4);
    prep_kernel<<<XB + 24 + EB, 256, 0, stream>>>(x, xb, W1l, W1r, W2l, W2r, Wb, dst, deg, XB, E);
    scan1_kernel<<<SB, 256, 0, stream>>>(deg, part, bsum, N_NODES);
    scan3_kernel<<<SB, 256, 0, stream>>>(part, bsum, row_ptr, SB, N_NODES);
    fill_kernel<<<EB, 256, 0, stream>>>(src, dst, row_ptr, cursor, esrc, E);

    // ---- layer 1 (+ t2 = h1·W2l^T) ----
    gather_bf16_kernel<16><<<GB, 256, 0, stream>>>(xb, row_ptr, esrc, aggb, N_NODES);
    layer1_mfma_kernel<<<MB, 64, 0, stream>>>(aggb, xb, Wb, b1, h1b, t2b);

    // ---- layer 2 (gather over 128B t2 rows) ----
    gather_bf16_kernel<8><<<GB, 256, 0, stream>>>(t2b, row_ptr, esrc, agg2b, N_NODES);
    layer2_mfma_kernel<<<MB, 64, 0, stream>>>(agg2b, h1b, Wb, b2, out);
}